// Round 4
// baseline (155.334 us; speedup 1.0000x reference)
//
#include <hip/hip_runtime.h>
#include <hip/hip_bf16.h>
#include <math.h>

#define NPTS 524288
#define HDIM 256
#define NBLK2 (NPTS / 512)        // main blocks, 2 points per thread
#define STEPS 100

constexpr float DXF        = (float)(20.0 / (NPTS - 1));
constexpr float DTF        = 0.01f;
constexpr float SQRT2DT    = 0.14142135623730951f;       // np.float32(sqrt(2*DT))
constexpr float TWO_LOG2E  = 2.8853900817779268f;        // 2*log2(e)
constexpr float LN2_O_2DX  = (float)(0.6931471805599453 / (2.0 * (20.0 / (NPTS - 1))));

typedef float v2f __attribute__((ext_vector_type(2)));

static __device__ __forceinline__ v2f vfma(v2f a, v2f b, v2f c) {
#if __has_builtin(__builtin_elementwise_fma)
    return __builtin_elementwise_fma(a, b, c);
#else
    v2f r; r.x = fmaf(a.x, b.x, c.x); r.y = fmaf(a.y, b.y, c.y); return r;
#endif
}

// ---------------------------------------------------------------------------
// Kernel 0: fold constants. wk (256 floats each): w1k|b1k|w20|w21|wg0|wg1
//   w1k = W1*2log2e, b1k = b1*2log2e, wg{0,1} = W2[:,{0,1}]*W1^2
// ---------------------------------------------------------------------------
__global__ void qpe_prep(const float* __restrict__ W1, const float* __restrict__ b1,
                         const float* __restrict__ W2, float* __restrict__ wk)
{
    const int h = threadIdx.x;
    const float w1  = W1[h];
    const float w20 = W2[2*h];
    const float w21 = W2[2*h + 1];
    const float w1s = w1 * w1;
    wk[h]        = w1 * TWO_LOG2E;
    wk[256 + h]  = b1[h] * TWO_LOG2E;
    wk[512 + h]  = w20;
    wk[768 + h]  = w21;
    wk[1024 + h] = w20 * w1s;
    wk[1280 + h] = w21 * w1s;
}

// ---------------------------------------------------------------------------
// Walk: one wave recomputes nd(c±1) from the weights each step — no loads in
// the dependent chain. Lane l covers h = l, l+64, l+128, l+192 for both
// points; butterfly-reduce; score via v_log_f32. Runs as block NBLK2 of
// qpe_main's grid, concurrent with (and hidden under) the main sweep.
// ---------------------------------------------------------------------------
static __device__ void qpe_walk(const float* __restrict__ x,
                                const float* __restrict__ wk,
                                const float* __restrict__ b2,
                                const float* __restrict__ noise,
                                const int*  __restrict__ init_idx,
                                float* __restrict__ out)
{
    const int lane = threadIdx.x & 63;
    float w1r[4], b1r[4], w20r[4], w21r[4];
    #pragma unroll
    for (int k = 0; k < 4; ++k) {
        const int h = lane + 64 * k;
        w1r[k]  = wk[h];
        b1r[k]  = wk[256 + h];
        w20r[k] = wk[512 + h];
        w21r[k] = wk[768 + h];
    }
    const float b20 = b2[0], b21 = b2[1];

    int c = init_idx[0];
    for (int t = 0; t < STEPS; ++t) {
        const float zs = __fmul_rn(noise[t], SQRT2DT);
        float s = 0.0f;
        if (c > 0 && c < NPTS - 1) {
            const float xm = fmaf((float)(c - 1), DXF, -10.0f);
            const float xp = fmaf((float)(c + 1), DXF, -10.0f);
            float P0m = 0.f, P1m = 0.f, P0p = 0.f, P1p = 0.f;
            #pragma unroll
            for (int k = 0; k < 4; ++k) {
                const float um = fmaf(xm, w1r[k], b1r[k]);
                const float up = fmaf(xp, w1r[k], b1r[k]);
                const float em = __builtin_amdgcn_exp2f(um);
                const float ep = __builtin_amdgcn_exp2f(up);
                const float rm = __builtin_amdgcn_rcpf(em + 1.0f);
                const float rp = __builtin_amdgcn_rcpf(ep + 1.0f);
                const float tm = fmaf(-2.0f, rm, 1.0f);
                const float tp = fmaf(-2.0f, rp, 1.0f);
                P0m = fmaf(w20r[k], tm, P0m);
                P1m = fmaf(w21r[k], tm, P1m);
                P0p = fmaf(w20r[k], tp, P0p);
                P1p = fmaf(w21r[k], tp, P1p);
            }
            #pragma unroll
            for (int off = 32; off; off >>= 1) {
                P0m += __shfl_xor(P0m, off);
                P1m += __shfl_xor(P1m, off);
                P0p += __shfl_xor(P0p, off);
                P1p += __shfl_xor(P1p, off);
            }
            const float p0m = b20 + P0m, p1m = b21 + P1m;
            const float p0p = b20 + P0p, p1p = b21 + P1p;
            const float ndm = fmaf(p0m, p0m, p1m * p1m);
            const float ndp = fmaf(p0p, p0p, p1p * p1p);
            const float l2m = __builtin_amdgcn_logf(ndm);   // log2
            const float l2p = __builtin_amdgcn_logf(ndp);
            s = __fmul_rn(__fsub_rn(l2p, l2m), LN2_O_2DX);
        }
        const float a = __fadd_rn(__fmul_rn(s, DTF), zs);
        const int shift = (int)__fdiv_rn(a, DXF);
        c += shift;
        c = c < 0 ? 0 : (c > NPTS - 1 ? NPTS - 1 : c);
    }
    if (lane == 0) out[2 * NPTS + 1] = x[c];
}

// ---------------------------------------------------------------------------
// Kernel 1: 2 grid points per thread. Packed fp32 over h-pairs; two
// independent trans chains per iteration hide exp2/rcp latency.
// ---------------------------------------------------------------------------
__global__ __launch_bounds__(256) void qpe_main(
    const float* __restrict__ x,  const float* __restrict__ V,
    const float* __restrict__ wk, const float* __restrict__ b2,
    float* __restrict__ out,      float* __restrict__ pdens,
    float* __restrict__ pnd,      const float* __restrict__ noise,
    const int* __restrict__ init_idx)
{
    if (blockIdx.x == NBLK2) {             // dedicated walk block
        if (threadIdx.x < 64)
            qpe_walk(x, wk, b2, noise, init_idx, out);
        return;
    }

    const int i = blockIdx.x * 256 + threadIdx.x;     // pair index
    const float2 xv = reinterpret_cast<const float2*>(x)[i];
    const float2 Vv = reinterpret_cast<const float2*>(V)[i];

    const v2f* __restrict__ w1k2 = (const v2f*)(wk);
    const v2f* __restrict__ b1k2 = (const v2f*)(wk + 256);
    const v2f* __restrict__ w202 = (const v2f*)(wk + 512);
    const v2f* __restrict__ w212 = (const v2f*)(wk + 768);
    const v2f* __restrict__ wg02 = (const v2f*)(wk + 1024);
    const v2f* __restrict__ wg12 = (const v2f*)(wk + 1280);

    const v2f xa   = {xv.x, xv.x};
    const v2f xb   = {xv.y, xv.y};
    const v2f one2 = {1.0f, 1.0f};
    const v2f m2   = {-2.0f, -2.0f};
    v2f pa0 = {0.f,0.f}, pa1 = {0.f,0.f}, aa0 = {0.f,0.f}, aa1 = {0.f,0.f};
    v2f pb0 = {0.f,0.f}, pb1 = {0.f,0.f}, ab0 = {0.f,0.f}, ab1 = {0.f,0.f};

    #pragma unroll 4
    for (int j = 0; j < HDIM / 2; ++j) {
        const v2f w1 = w1k2[j];
        const v2f bb = b1k2[j];
        const v2f ua = vfma(xa, w1, bb);
        const v2f ub = vfma(xb, w1, bb);
        v2f ea, eb;
        ea.x = __builtin_amdgcn_exp2f(ua.x); ea.y = __builtin_amdgcn_exp2f(ua.y);
        eb.x = __builtin_amdgcn_exp2f(ub.x); eb.y = __builtin_amdgcn_exp2f(ub.y);
        const v2f da = ea + one2;
        const v2f db = eb + one2;
        v2f ra, rb;
        ra.x = __builtin_amdgcn_rcpf(da.x); ra.y = __builtin_amdgcn_rcpf(da.y);
        rb.x = __builtin_amdgcn_rcpf(db.x); rb.y = __builtin_amdgcn_rcpf(db.y);
        const v2f ta = vfma(m2, ra, one2);
        const v2f tb = vfma(m2, rb, one2);
        const v2f oa = vfma(-ta, ta, one2);
        const v2f ob = vfma(-tb, tb, one2);
        const v2f ga = ta * oa;
        const v2f gb = tb * ob;
        const v2f w20 = w202[j], w21 = w212[j];
        const v2f g0  = wg02[j], g1  = wg12[j];
        pa0 = vfma(w20, ta, pa0);  pa1 = vfma(w21, ta, pa1);
        aa0 = vfma(g0,  ga, aa0);  aa1 = vfma(g1,  ga, aa1);
        pb0 = vfma(w20, tb, pb0);  pb1 = vfma(w21, tb, pb1);
        ab0 = vfma(g0,  gb, ab0);  ab1 = vfma(g1,  gb, ab1);
    }

    const float b20 = b2[0], b21 = b2[1];
    const float psiA0 = pa0.x + pa0.y + b20;
    const float psiA1 = pa1.x + pa1.y + b21;
    const float psiB0 = pb0.x + pb0.y + b20;
    const float psiB1 = pb1.x + pb1.y + b21;
    const float taA0 = aa0.x + aa0.y, taA1 = aa1.x + aa1.y;
    const float taB0 = ab0.x + ab0.y, taB1 = ab1.x + ab1.y;

    const float hpA0 = fmaf(Vv.x, psiA0, taA0);
    const float hpA1 = fmaf(Vv.x, psiA1, taA1);
    const float hpB0 = fmaf(Vv.y, psiB0, taB0);
    const float hpB1 = fmaf(Vv.y, psiB1, taB1);
    float4 o4; o4.x = hpA0; o4.y = hpA1; o4.z = hpB0; o4.w = hpB1;
    reinterpret_cast<float4*>(out)[i] = o4;

    const float ndA = fmaf(psiA0, psiA0, psiA1 * psiA1);
    const float ndB = fmaf(psiB0, psiB0, psiB1 * psiB1);
    float dens = fmaf(psiA0, hpA0, psiA1 * hpA1) + fmaf(psiB0, hpB0, psiB1 * hpB1);
    float ndr  = ndA + ndB;

    #pragma unroll
    for (int off = 32; off; off >>= 1) {
        dens += __shfl_down(dens, off);
        ndr  += __shfl_down(ndr, off);
    }
    __shared__ float sd[4], sn[4];
    const int lane = threadIdx.x & 63;
    const int wid  = threadIdx.x >> 6;
    if (lane == 0) { sd[wid] = dens; sn[wid] = ndr; }
    __syncthreads();
    if (threadIdx.x == 0) {
        pdens[blockIdx.x] = sd[0] + sd[1] + sd[2] + sd[3];
        pnd[blockIdx.x]   = sn[0] + sn[1] + sn[2] + sn[3];
    }
}

// ---------------------------------------------------------------------------
// Kernel 2: reduce 1024 block partials -> energy
// ---------------------------------------------------------------------------
__global__ __launch_bounds__(256) void qpe_reduce(
    const float* __restrict__ pdens, const float* __restrict__ pnd,
    float* __restrict__ energy_out)
{
    const int tid = threadIdx.x;
    float d = pdens[tid] + pdens[tid + 256] + pdens[tid + 512] + pdens[tid + 768];
    float n = pnd[tid]   + pnd[tid + 256]   + pnd[tid + 512]   + pnd[tid + 768];
    #pragma unroll
    for (int off = 32; off; off >>= 1) {
        d += __shfl_down(d, off);
        n += __shfl_down(n, off);
    }
    __shared__ float sd[4], sn[4];
    const int lane = tid & 63;
    const int wid  = tid >> 6;
    if (lane == 0) { sd[wid] = d; sn[wid] = n; }
    __syncthreads();
    if (tid == 0) {
        const float Sd = sd[0] + sd[1] + sd[2] + sd[3];
        const float Sn = sn[0] + sn[1] + sn[2] + sn[3];
        energy_out[0] = __fdiv_rn(Sd * DXF, fmaf(Sn, DXF, 1e-8f));
    }
}

// ---------------------------------------------------------------------------
extern "C" void kernel_launch(void* const* d_in, const int* in_sizes, int n_in,
                              void* d_out, int out_size, void* d_ws, size_t ws_size,
                              hipStream_t stream) {
    const float* x        = (const float*)d_in[0];
    const float* V        = (const float*)d_in[1];
    const float* W1       = (const float*)d_in[2];
    const float* b1       = (const float*)d_in[3];
    const float* W2       = (const float*)d_in[4];
    const float* b2       = (const float*)d_in[5];
    const float* noise    = (const float*)d_in[6];
    const int*   init_idx = (const int*)d_in[7];

    float* out = (float*)d_out;
    float* ws  = (float*)d_ws;

    float* wk    = ws;            // 1536
    float* pdens = ws + 2048;     // 1024
    float* pnd   = ws + 4096;     // 1024

    qpe_prep<<<1, 256, 0, stream>>>(W1, b1, W2, wk);
    qpe_main<<<NBLK2 + 1, 256, 0, stream>>>(x, V, wk, b2, out, pdens, pnd,
                                            noise, init_idx);
    qpe_reduce<<<1, 256, 0, stream>>>(pdens, pnd, out + 2 * NPTS);
}

// Round 5
// 141.580 us; speedup vs baseline: 1.0972x; 1.0972x over previous
//
#include <hip/hip_runtime.h>
#include <hip/hip_bf16.h>
#include <math.h>

#define NPTS 524288
#define HDIM 256
#define NBLK2 (NPTS / 512)        // main blocks, 2 points per thread
#define STEPS 100

constexpr float DXF        = (float)(20.0 / (NPTS - 1));
constexpr float DTF        = 0.01f;
constexpr float SQRT2DT    = 0.14142135623730951f;       // np.float32(sqrt(2*DT))
constexpr float TWO_LOG2E  = 2.8853900817779268f;        // 2*log2(e)
constexpr float LN2_O_2DX  = (float)(0.6931471805599453 / (2.0 * (20.0 / (NPTS - 1))));

typedef float v2f __attribute__((ext_vector_type(2)));

static __device__ __forceinline__ v2f vfma(v2f a, v2f b, v2f c) {
#if __has_builtin(__builtin_elementwise_fma)
    return __builtin_elementwise_fma(a, b, c);
#else
    v2f r; r.x = fmaf(a.x, b.x, c.x); r.y = fmaf(a.y, b.y, c.y); return r;
#endif
}

// DPP in-register wave reduce: 4 row_shr adds collapse each 16-lane row
// (sum lands in lanes 15/31/47/63), then 4 readlanes + scalar adds.
// Pure VALU (~2-4 cy/op) vs ds_swizzle butterfly (~100+ cy/level).
template <int CTRL>
static __device__ __forceinline__ float dppadd(float x) {
    return __fadd_rn(x, __int_as_float(
        __builtin_amdgcn_update_dpp(0, __float_as_int(x), CTRL, 0xf, 0xf, true)));
}
static __device__ __forceinline__ float row_tot(float x) {
    x = dppadd<0x111>(x);   // row_shr:1
    x = dppadd<0x112>(x);   // row_shr:2
    x = dppadd<0x114>(x);   // row_shr:4
    x = dppadd<0x118>(x);   // row_shr:8
    const float a = __int_as_float(__builtin_amdgcn_readlane(__float_as_int(x), 15));
    const float b = __int_as_float(__builtin_amdgcn_readlane(__float_as_int(x), 31));
    const float c = __int_as_float(__builtin_amdgcn_readlane(__float_as_int(x), 47));
    const float d = __int_as_float(__builtin_amdgcn_readlane(__float_as_int(x), 63));
    return (a + b) + (c + d);
}

// ---------------------------------------------------------------------------
// Kernel 0: fold constants. wk (256 floats each): w1k|b1k|w20|w21|wg0|wg1
//   w1k = W1*2log2e, b1k = b1*2log2e, wg{0,1} = W2[:,{0,1}]*W1^2
// ---------------------------------------------------------------------------
__global__ void qpe_prep(const float* __restrict__ W1, const float* __restrict__ b1,
                         const float* __restrict__ W2, float* __restrict__ wk)
{
    const int h = threadIdx.x;
    const float w1  = W1[h];
    const float w20 = W2[2*h];
    const float w21 = W2[2*h + 1];
    const float w1s = w1 * w1;
    wk[h]        = w1 * TWO_LOG2E;
    wk[256 + h]  = b1[h] * TWO_LOG2E;
    wk[512 + h]  = w20;
    wk[768 + h]  = w21;
    wk[1024 + h] = w20 * w1s;
    wk[1280 + h] = w21 * w1s;
}

// ---------------------------------------------------------------------------
// Walk: one wave recomputes nd(c±1) from weights each step — no loads in the
// dependent chain (noise is prefetched one step ahead). Lane l covers
// h = l + 64k, k=0..3; DPP row-reduce + readlane; score via v_log_f32.
// Runs as the last block of qpe_main's grid, hidden under the main sweep.
// ---------------------------------------------------------------------------
static __device__ void qpe_walk(const float* __restrict__ x,
                                const float* __restrict__ wk,
                                const float* __restrict__ b2,
                                const float* __restrict__ noise,
                                const int*  __restrict__ init_idx,
                                float* __restrict__ out)
{
    const int lane = threadIdx.x & 63;
    float w1r[4], b1r[4], w20r[4], w21r[4];
    #pragma unroll
    for (int k = 0; k < 4; ++k) {
        const int h = lane + 64 * k;
        w1r[k]  = wk[h];
        b1r[k]  = wk[256 + h];
        w20r[k] = wk[512 + h];
        w21r[k] = wk[768 + h];
    }
    const float b20 = b2[0], b21 = b2[1];

    int c = init_idx[0];
    float zn = noise[0];                     // prefetched noise value
    for (int t = 0; t < STEPS; ++t) {
        const float zs = __fmul_rn(zn, SQRT2DT);
        const int tn = (t + 1 < STEPS) ? t + 1 : t;
        zn = noise[tn];                      // issue now, consume next iter
        float s = 0.0f;
        if (c > 0 && c < NPTS - 1) {
            const float xm = fmaf((float)(c - 1), DXF, -10.0f);
            const float xp = fmaf((float)(c + 1), DXF, -10.0f);
            float P0m = 0.f, P1m = 0.f, P0p = 0.f, P1p = 0.f;
            #pragma unroll
            for (int k = 0; k < 4; ++k) {
                const float um = fmaf(xm, w1r[k], b1r[k]);
                const float up = fmaf(xp, w1r[k], b1r[k]);
                const float em = __builtin_amdgcn_exp2f(um);
                const float ep = __builtin_amdgcn_exp2f(up);
                const float rm = __builtin_amdgcn_rcpf(em + 1.0f);
                const float rp = __builtin_amdgcn_rcpf(ep + 1.0f);
                const float tm = fmaf(-2.0f, rm, 1.0f);
                const float tp = fmaf(-2.0f, rp, 1.0f);
                P0m = fmaf(w20r[k], tm, P0m);
                P1m = fmaf(w21r[k], tm, P1m);
                P0p = fmaf(w20r[k], tp, P0p);
                P1p = fmaf(w21r[k], tp, P1p);
            }
            const float S0m = row_tot(P0m);
            const float S1m = row_tot(P1m);
            const float S0p = row_tot(P0p);
            const float S1p = row_tot(P1p);
            const float p0m = b20 + S0m, p1m = b21 + S1m;
            const float p0p = b20 + S0p, p1p = b21 + S1p;
            const float ndm = fmaf(p0m, p0m, p1m * p1m);
            const float ndp = fmaf(p0p, p0p, p1p * p1p);
            const float l2m = __builtin_amdgcn_logf(ndm);   // log2
            const float l2p = __builtin_amdgcn_logf(ndp);
            s = __fmul_rn(__fsub_rn(l2p, l2m), LN2_O_2DX);
        }
        const float a = __fadd_rn(__fmul_rn(s, DTF), zs);
        const int shift = (int)__fdiv_rn(a, DXF);
        c += shift;
        c = c < 0 ? 0 : (c > NPTS - 1 ? NPTS - 1 : c);
    }
    if (lane == 0) out[2 * NPTS + 1] = x[c];
}

// ---------------------------------------------------------------------------
// Kernel 1: 2 grid points per thread. Packed fp32 over h-pairs; two
// independent trans chains per iteration hide exp2/rcp latency.
// ---------------------------------------------------------------------------
__global__ __launch_bounds__(256) void qpe_main(
    const float* __restrict__ x,  const float* __restrict__ V,
    const float* __restrict__ wk, const float* __restrict__ b2,
    float* __restrict__ out,      float* __restrict__ pdens,
    float* __restrict__ pnd,      const float* __restrict__ noise,
    const int* __restrict__ init_idx)
{
    if (blockIdx.x == NBLK2) {             // dedicated walk block
        if (threadIdx.x < 64)
            qpe_walk(x, wk, b2, noise, init_idx, out);
        return;
    }

    const int i = blockIdx.x * 256 + threadIdx.x;     // pair index
    const float2 xv = reinterpret_cast<const float2*>(x)[i];
    const float2 Vv = reinterpret_cast<const float2*>(V)[i];

    const v2f* __restrict__ w1k2 = (const v2f*)(wk);
    const v2f* __restrict__ b1k2 = (const v2f*)(wk + 256);
    const v2f* __restrict__ w202 = (const v2f*)(wk + 512);
    const v2f* __restrict__ w212 = (const v2f*)(wk + 768);
    const v2f* __restrict__ wg02 = (const v2f*)(wk + 1024);
    const v2f* __restrict__ wg12 = (const v2f*)(wk + 1280);

    const v2f xa   = {xv.x, xv.x};
    const v2f xb   = {xv.y, xv.y};
    const v2f one2 = {1.0f, 1.0f};
    const v2f m2   = {-2.0f, -2.0f};
    v2f pa0 = {0.f,0.f}, pa1 = {0.f,0.f}, aa0 = {0.f,0.f}, aa1 = {0.f,0.f};
    v2f pb0 = {0.f,0.f}, pb1 = {0.f,0.f}, ab0 = {0.f,0.f}, ab1 = {0.f,0.f};

    #pragma unroll 4
    for (int j = 0; j < HDIM / 2; ++j) {
        const v2f w1 = w1k2[j];
        const v2f bb = b1k2[j];
        const v2f ua = vfma(xa, w1, bb);
        const v2f ub = vfma(xb, w1, bb);
        v2f ea, eb;
        ea.x = __builtin_amdgcn_exp2f(ua.x); ea.y = __builtin_amdgcn_exp2f(ua.y);
        eb.x = __builtin_amdgcn_exp2f(ub.x); eb.y = __builtin_amdgcn_exp2f(ub.y);
        const v2f da = ea + one2;
        const v2f db = eb + one2;
        v2f ra, rb;
        ra.x = __builtin_amdgcn_rcpf(da.x); ra.y = __builtin_amdgcn_rcpf(da.y);
        rb.x = __builtin_amdgcn_rcpf(db.x); rb.y = __builtin_amdgcn_rcpf(db.y);
        const v2f ta = vfma(m2, ra, one2);
        const v2f tb = vfma(m2, rb, one2);
        const v2f oa = vfma(-ta, ta, one2);
        const v2f ob = vfma(-tb, tb, one2);
        const v2f ga = ta * oa;
        const v2f gb = tb * ob;
        const v2f w20 = w202[j], w21 = w212[j];
        const v2f g0  = wg02[j], g1  = wg12[j];
        pa0 = vfma(w20, ta, pa0);  pa1 = vfma(w21, ta, pa1);
        aa0 = vfma(g0,  ga, aa0);  aa1 = vfma(g1,  ga, aa1);
        pb0 = vfma(w20, tb, pb0);  pb1 = vfma(w21, tb, pb1);
        ab0 = vfma(g0,  gb, ab0);  ab1 = vfma(g1,  gb, ab1);
    }

    const float b20 = b2[0], b21 = b2[1];
    const float psiA0 = pa0.x + pa0.y + b20;
    const float psiA1 = pa1.x + pa1.y + b21;
    const float psiB0 = pb0.x + pb0.y + b20;
    const float psiB1 = pb1.x + pb1.y + b21;
    const float taA0 = aa0.x + aa0.y, taA1 = aa1.x + aa1.y;
    const float taB0 = ab0.x + ab0.y, taB1 = ab1.x + ab1.y;

    const float hpA0 = fmaf(Vv.x, psiA0, taA0);
    const float hpA1 = fmaf(Vv.x, psiA1, taA1);
    const float hpB0 = fmaf(Vv.y, psiB0, taB0);
    const float hpB1 = fmaf(Vv.y, psiB1, taB1);
    float4 o4; o4.x = hpA0; o4.y = hpA1; o4.z = hpB0; o4.w = hpB1;
    reinterpret_cast<float4*>(out)[i] = o4;

    const float ndA = fmaf(psiA0, psiA0, psiA1 * psiA1);
    const float ndB = fmaf(psiB0, psiB0, psiB1 * psiB1);
    float dens = fmaf(psiA0, hpA0, psiA1 * hpA1) + fmaf(psiB0, hpB0, psiB1 * hpB1);
    float ndr  = ndA + ndB;

    #pragma unroll
    for (int off = 32; off; off >>= 1) {
        dens += __shfl_down(dens, off);
        ndr  += __shfl_down(ndr, off);
    }
    __shared__ float sd[4], sn[4];
    const int lane = threadIdx.x & 63;
    const int wid  = threadIdx.x >> 6;
    if (lane == 0) { sd[wid] = dens; sn[wid] = ndr; }
    __syncthreads();
    if (threadIdx.x == 0) {
        pdens[blockIdx.x] = sd[0] + sd[1] + sd[2] + sd[3];
        pnd[blockIdx.x]   = sn[0] + sn[1] + sn[2] + sn[3];
    }
}

// ---------------------------------------------------------------------------
// Kernel 2: reduce 1024 block partials -> energy
// ---------------------------------------------------------------------------
__global__ __launch_bounds__(256) void qpe_reduce(
    const float* __restrict__ pdens, const float* __restrict__ pnd,
    float* __restrict__ energy_out)
{
    const int tid = threadIdx.x;
    float d = pdens[tid] + pdens[tid + 256] + pdens[tid + 512] + pdens[tid + 768];
    float n = pnd[tid]   + pnd[tid + 256]   + pnd[tid + 512]   + pnd[tid + 768];
    #pragma unroll
    for (int off = 32; off; off >>= 1) {
        d += __shfl_down(d, off);
        n += __shfl_down(n, off);
    }
    __shared__ float sd[4], sn[4];
    const int lane = tid & 63;
    const int wid  = tid >> 6;
    if (lane == 0) { sd[wid] = d; sn[wid] = n; }
    __syncthreads();
    if (tid == 0) {
        const float Sd = sd[0] + sd[1] + sd[2] + sd[3];
        const float Sn = sn[0] + sn[1] + sn[2] + sn[3];
        energy_out[0] = __fdiv_rn(Sd * DXF, fmaf(Sn, DXF, 1e-8f));
    }
}

// ---------------------------------------------------------------------------
extern "C" void kernel_launch(void* const* d_in, const int* in_sizes, int n_in,
                              void* d_out, int out_size, void* d_ws, size_t ws_size,
                              hipStream_t stream) {
    const float* x        = (const float*)d_in[0];
    const float* V        = (const float*)d_in[1];
    const float* W1       = (const float*)d_in[2];
    const float* b1       = (const float*)d_in[3];
    const float* W2       = (const float*)d_in[4];
    const float* b2       = (const float*)d_in[5];
    const float* noise    = (const float*)d_in[6];
    const int*   init_idx = (const int*)d_in[7];

    float* out = (float*)d_out;
    float* ws  = (float*)d_ws;

    float* wk    = ws;            // 1536
    float* pdens = ws + 2048;     // 1024
    float* pnd   = ws + 4096;     // 1024

    qpe_prep<<<1, 256, 0, stream>>>(W1, b1, W2, wk);
    qpe_main<<<NBLK2 + 1, 256, 0, stream>>>(x, V, wk, b2, out, pdens, pnd,
                                            noise, init_idx);
    qpe_reduce<<<1, 256, 0, stream>>>(pdens, pnd, out + 2 * NPTS);
}

// Round 6
// 137.124 us; speedup vs baseline: 1.1328x; 1.0325x over previous
//
#include <hip/hip_runtime.h>
#include <hip/hip_bf16.h>
#include <math.h>

#define NPTS 524288
#define HDIM 256
#define NBLK2 (NPTS / 512)        // main blocks, 2 points per thread
#define STEPS 100

constexpr float DXF        = (float)(20.0 / (NPTS - 1));
constexpr float DTF        = 0.01f;
constexpr float SQRT2DT    = 0.14142135623730951f;       // np.float32(sqrt(2*DT))
constexpr float TWO_LOG2E  = 2.8853900817779268f;        // 2*log2(e)
constexpr float LN2_O_2DX  = (float)(0.6931471805599453 / (2.0 * (20.0 / (NPTS - 1))));

typedef float v2f __attribute__((ext_vector_type(2)));

static __device__ __forceinline__ v2f vfma(v2f a, v2f b, v2f c) {
#if __has_builtin(__builtin_elementwise_fma)
    return __builtin_elementwise_fma(a, b, c);
#else
    v2f r; r.x = fmaf(a.x, b.x, c.x); r.y = fmaf(a.y, b.y, c.y); return r;
#endif
}

// ---------------------------------------------------------------------------
// Kernel 0: fold constants. wk (256 floats each): w1k|b1k|w20|w21|wg0|wg1
// ---------------------------------------------------------------------------
__global__ void qpe_prep(const float* __restrict__ W1, const float* __restrict__ b1,
                         const float* __restrict__ W2, float* __restrict__ wk)
{
    const int h = threadIdx.x;
    const float w1  = W1[h];
    const float w20 = W2[2*h];
    const float w21 = W2[2*h + 1];
    const float w1s = w1 * w1;
    wk[h]        = w1 * TWO_LOG2E;
    wk[256 + h]  = b1[h] * TWO_LOG2E;
    wk[512 + h]  = w20;
    wk[768 + h]  = w21;
    wk[1024 + h] = w20 * w1s;
    wk[1280 + h] = w21 * w1s;
}

// ---------------------------------------------------------------------------
// Kernel 1: 2 grid points per thread, packed fp32 over h-pairs. Writes
// h_psi, lp2 = log2(nd) (feeds the walk's lookup), and block partials.
// ---------------------------------------------------------------------------
__global__ __launch_bounds__(256) void qpe_main(
    const float* __restrict__ x,  const float* __restrict__ V,
    const float* __restrict__ wk, const float* __restrict__ b2,
    float* __restrict__ out,      float* __restrict__ lp2,
    float* __restrict__ pdens,    float* __restrict__ pnd)
{
    const int i = blockIdx.x * 256 + threadIdx.x;     // pair index
    const float2 xv = reinterpret_cast<const float2*>(x)[i];
    const float2 Vv = reinterpret_cast<const float2*>(V)[i];

    const v2f* __restrict__ w1k2 = (const v2f*)(wk);
    const v2f* __restrict__ b1k2 = (const v2f*)(wk + 256);
    const v2f* __restrict__ w202 = (const v2f*)(wk + 512);
    const v2f* __restrict__ w212 = (const v2f*)(wk + 768);
    const v2f* __restrict__ wg02 = (const v2f*)(wk + 1024);
    const v2f* __restrict__ wg12 = (const v2f*)(wk + 1280);

    const v2f xa   = {xv.x, xv.x};
    const v2f xb   = {xv.y, xv.y};
    const v2f one2 = {1.0f, 1.0f};
    const v2f m2   = {-2.0f, -2.0f};
    v2f pa0 = {0.f,0.f}, pa1 = {0.f,0.f}, aa0 = {0.f,0.f}, aa1 = {0.f,0.f};
    v2f pb0 = {0.f,0.f}, pb1 = {0.f,0.f}, ab0 = {0.f,0.f}, ab1 = {0.f,0.f};

    #pragma unroll 4
    for (int j = 0; j < HDIM / 2; ++j) {
        const v2f w1 = w1k2[j];
        const v2f bb = b1k2[j];
        const v2f ua = vfma(xa, w1, bb);
        const v2f ub = vfma(xb, w1, bb);
        v2f ea, eb;
        ea.x = __builtin_amdgcn_exp2f(ua.x); ea.y = __builtin_amdgcn_exp2f(ua.y);
        eb.x = __builtin_amdgcn_exp2f(ub.x); eb.y = __builtin_amdgcn_exp2f(ub.y);
        const v2f da = ea + one2;
        const v2f db = eb + one2;
        v2f ra, rb;
        ra.x = __builtin_amdgcn_rcpf(da.x); ra.y = __builtin_amdgcn_rcpf(da.y);
        rb.x = __builtin_amdgcn_rcpf(db.x); rb.y = __builtin_amdgcn_rcpf(db.y);
        const v2f ta = vfma(m2, ra, one2);
        const v2f tb = vfma(m2, rb, one2);
        const v2f oa = vfma(-ta, ta, one2);
        const v2f ob = vfma(-tb, tb, one2);
        const v2f ga = ta * oa;
        const v2f gb = tb * ob;
        const v2f w20 = w202[j], w21 = w212[j];
        const v2f g0  = wg02[j], g1  = wg12[j];
        pa0 = vfma(w20, ta, pa0);  pa1 = vfma(w21, ta, pa1);
        aa0 = vfma(g0,  ga, aa0);  aa1 = vfma(g1,  ga, aa1);
        pb0 = vfma(w20, tb, pb0);  pb1 = vfma(w21, tb, pb1);
        ab0 = vfma(g0,  gb, ab0);  ab1 = vfma(g1,  gb, ab1);
    }

    const float b20 = b2[0], b21 = b2[1];
    const float psiA0 = pa0.x + pa0.y + b20;
    const float psiA1 = pa1.x + pa1.y + b21;
    const float psiB0 = pb0.x + pb0.y + b20;
    const float psiB1 = pb1.x + pb1.y + b21;
    const float taA0 = aa0.x + aa0.y, taA1 = aa1.x + aa1.y;
    const float taB0 = ab0.x + ab0.y, taB1 = ab1.x + ab1.y;

    const float hpA0 = fmaf(Vv.x, psiA0, taA0);
    const float hpA1 = fmaf(Vv.x, psiA1, taA1);
    const float hpB0 = fmaf(Vv.y, psiB0, taB0);
    const float hpB1 = fmaf(Vv.y, psiB1, taB1);
    float4 o4; o4.x = hpA0; o4.y = hpA1; o4.z = hpB0; o4.w = hpB1;
    reinterpret_cast<float4*>(out)[i] = o4;

    const float ndA = fmaf(psiA0, psiA0, psiA1 * psiA1);
    const float ndB = fmaf(psiB0, psiB0, psiB1 * psiB1);
    float2 l2; l2.x = __builtin_amdgcn_logf(ndA);   // log2(nd)
    l2.y = __builtin_amdgcn_logf(ndB);
    reinterpret_cast<float2*>(lp2)[i] = l2;

    float dens = fmaf(psiA0, hpA0, psiA1 * hpA1) + fmaf(psiB0, hpB0, psiB1 * hpB1);
    float ndr  = ndA + ndB;

    #pragma unroll
    for (int off = 32; off; off >>= 1) {
        dens += __shfl_down(dens, off);
        ndr  += __shfl_down(ndr, off);
    }
    __shared__ float sd[4], sn[4];
    const int lane = threadIdx.x & 63;
    const int wid  = threadIdx.x >> 6;
    if (lane == 0) { sd[wid] = dens; sn[wid] = ndr; }
    __syncthreads();
    if (threadIdx.x == 0) {
        pdens[blockIdx.x] = sd[0] + sd[1] + sd[2] + sd[3];
        pnd[blockIdx.x]   = sn[0] + sn[1] + sn[2] + sn[3];
    }
}

// ---------------------------------------------------------------------------
// Kernel 2, 2 blocks:
//   block0          : reduce 1024 partials -> energy
//   block1 wave0.l0 : 100-step lookup walk on lp2 (short dependent chain:
//                     2 adjacent loads + ~10 VALU per step)
//   block1 waves1-3 : warm a 1 MB lp2 window around init_idx into this
//                     XCD's L2 (covers >3 sigma of the walk's diffusion;
//                     sized to finish before the walk does)
// ---------------------------------------------------------------------------
__global__ __launch_bounds__(256) void qpe_tail(
    const float* __restrict__ x,     const float* __restrict__ lp2,
    const float* __restrict__ pdens, const float* __restrict__ pnd,
    const float* __restrict__ noise, const int* __restrict__ init_idx,
    float* __restrict__ out,         float* __restrict__ dummy)
{
    const int tid = threadIdx.x;
    if (blockIdx.x == 0) {
        float d = pdens[tid] + pdens[tid + 256] + pdens[tid + 512] + pdens[tid + 768];
        float n = pnd[tid]   + pnd[tid + 256]   + pnd[tid + 512]   + pnd[tid + 768];
        #pragma unroll
        for (int off = 32; off; off >>= 1) {
            d += __shfl_down(d, off);
            n += __shfl_down(n, off);
        }
        __shared__ float sd[4], sn[4];
        const int lane = tid & 63;
        const int wid  = tid >> 6;
        if (lane == 0) { sd[wid] = d; sn[wid] = n; }
        __syncthreads();
        if (tid == 0) {
            const float Sd = sd[0] + sd[1] + sd[2] + sd[3];
            const float Sn = sn[0] + sn[1] + sn[2] + sn[3];
            out[2 * NPTS] = __fdiv_rn(Sd * DXF, fmaf(Sn, DXF, 1e-8f));
        }
        return;
    }

    if (tid == 0) {
        int c = init_idx[0];
        float zn = noise[0];
        for (int t = 0; t < STEPS; ++t) {
            const float zs = __fmul_rn(zn, SQRT2DT);
            const int tn = (t + 1 < STEPS) ? t + 1 : t;
            zn = noise[tn];                  // prefetch next step's noise
            float s = 0.0f;
            if (c > 0 && c < NPTS - 1) {
                const float l2m = lp2[c - 1];
                const float l2p = lp2[c + 1];
                s = __fmul_rn(__fsub_rn(l2p, l2m), LN2_O_2DX);
            }
            const float a = __fadd_rn(__fmul_rn(s, DTF), zs);
            const int shift = (int)__fdiv_rn(a, DXF);
            c += shift;
            c = c < 0 ? 0 : (c > NPTS - 1 ? NPTS - 1 : c);
        }
        out[2 * NPTS + 1] = x[c];
    } else if (tid >= 64) {
        // warm 1 MB (256K floats = 64K float4) of lp2 around init_idx
        int c0 = init_idx[0];
        int s4 = c0 / 4 - 32768;             // window start in float4 units
        if (s4 < 0) s4 = 0;
        if (s4 > NPTS / 4 - 65536) s4 = NPTS / 4 - 65536;
        const float4* __restrict__ src = (const float4*)lp2 + s4;
        const int l = tid - 64;              // 0..191
        float acc = 0.f;
        #pragma unroll 4
        for (int k = l; k < 65536; k += 192) {
            const float4 v = src[k];
            acc += v.x + v.y + v.z + v.w;
        }
        if (acc == 123456.789f) dummy[0] = acc;   // keep loads alive
    }
}

// ---------------------------------------------------------------------------
extern "C" void kernel_launch(void* const* d_in, const int* in_sizes, int n_in,
                              void* d_out, int out_size, void* d_ws, size_t ws_size,
                              hipStream_t stream) {
    const float* x        = (const float*)d_in[0];
    const float* V        = (const float*)d_in[1];
    const float* W1       = (const float*)d_in[2];
    const float* b1       = (const float*)d_in[3];
    const float* W2       = (const float*)d_in[4];
    const float* b2       = (const float*)d_in[5];
    const float* noise    = (const float*)d_in[6];
    const int*   init_idx = (const int*)d_in[7];

    float* out = (float*)d_out;
    float* ws  = (float*)d_ws;

    float* lp2   = ws;                    // N floats (2 MB)
    float* wk    = ws + NPTS;             // 1536
    float* pdens = ws + NPTS + 2048;      // 1024
    float* pnd   = ws + NPTS + 3072;      // 1024
    float* dummy = ws + NPTS + 4096;      // 1

    qpe_prep<<<1, 256, 0, stream>>>(W1, b1, W2, wk);
    qpe_main<<<NBLK2, 256, 0, stream>>>(x, V, wk, b2, out, lp2, pdens, pnd);
    qpe_tail<<<2, 256, 0, stream>>>(x, lp2, pdens, pnd, noise, init_idx,
                                    out, dummy);
}

// Round 7
// 133.542 us; speedup vs baseline: 1.1632x; 1.0268x over previous
//
#include <hip/hip_runtime.h>
#include <hip/hip_bf16.h>
#include <math.h>

#define NPTS 524288
#define HDIM 256
#define NBLK4 (NPTS / 1024)       // main blocks, 4 points per thread
#define STEPS 100

constexpr float DXF        = (float)(20.0 / (NPTS - 1));
constexpr float DTF        = 0.01f;
constexpr float SQRT2DT    = 0.14142135623730951f;       // np.float32(sqrt(2*DT))
constexpr float TWO_LOG2E  = 2.8853900817779268f;        // 2*log2(e)
constexpr float LN2_O_2DX  = (float)(0.6931471805599453 / (2.0 * (20.0 / (NPTS - 1))));

typedef float v2f __attribute__((ext_vector_type(2)));

static __device__ __forceinline__ v2f vfma(v2f a, v2f b, v2f c) {
#if __has_builtin(__builtin_elementwise_fma)
    return __builtin_elementwise_fma(a, b, c);
#else
    v2f r; r.x = fmaf(a.x, b.x, c.x); r.y = fmaf(a.y, b.y, c.y); return r;
#endif
}

// ---------------------------------------------------------------------------
// Kernel 0: fold constants. wk (256 floats each): w1k|b1k|w20|w21|wg0|wg1
// ---------------------------------------------------------------------------
__global__ void qpe_prep(const float* __restrict__ W1, const float* __restrict__ b1,
                         const float* __restrict__ W2, float* __restrict__ wk)
{
    const int h = threadIdx.x;
    const float w1  = W1[h];
    const float w20 = W2[2*h];
    const float w21 = W2[2*h + 1];
    const float w1s = w1 * w1;
    wk[h]        = w1 * TWO_LOG2E;
    wk[256 + h]  = b1[h] * TWO_LOG2E;
    wk[512 + h]  = w20;
    wk[768 + h]  = w21;
    wk[1024 + h] = w20 * w1s;
    wk[1280 + h] = w21 * w1s;
}

// ---------------------------------------------------------------------------
// Kernel 1: 4 grid points per thread (float4 I/O), packed fp32 over h-pairs.
// 4 independent exp2->rcp chains per thread keep the quarter-rate trans
// pipe's issue slots filled. Writes h_psi, lp2 = log2(nd), block partials.
// ---------------------------------------------------------------------------
__global__ __launch_bounds__(256) void qpe_main(
    const float* __restrict__ x,  const float* __restrict__ V,
    const float* __restrict__ wk, const float* __restrict__ b2,
    float* __restrict__ out,      float* __restrict__ lp2,
    float* __restrict__ pdens,    float* __restrict__ pnd)
{
    const int i = blockIdx.x * 256 + threadIdx.x;     // quad index
    const float4 xv = reinterpret_cast<const float4*>(x)[i];
    const float4 Vv = reinterpret_cast<const float4*>(V)[i];

    const v2f* __restrict__ w1k2 = (const v2f*)(wk);
    const v2f* __restrict__ b1k2 = (const v2f*)(wk + 256);
    const v2f* __restrict__ w202 = (const v2f*)(wk + 512);
    const v2f* __restrict__ w212 = (const v2f*)(wk + 768);
    const v2f* __restrict__ wg02 = (const v2f*)(wk + 1024);
    const v2f* __restrict__ wg12 = (const v2f*)(wk + 1280);

    const v2f one2 = {1.0f, 1.0f};
    const v2f m2   = {-2.0f, -2.0f};
    v2f xq[4];
    xq[0] = (v2f){xv.x, xv.x};  xq[1] = (v2f){xv.y, xv.y};
    xq[2] = (v2f){xv.z, xv.z};  xq[3] = (v2f){xv.w, xv.w};

    v2f P0[4], P1[4], A0[4], A1[4];
    #pragma unroll
    for (int q = 0; q < 4; ++q) {
        P0[q] = (v2f){0.f, 0.f}; P1[q] = (v2f){0.f, 0.f};
        A0[q] = (v2f){0.f, 0.f}; A1[q] = (v2f){0.f, 0.f};
    }

    #pragma unroll 2
    for (int j = 0; j < HDIM / 2; ++j) {
        const v2f w1 = w1k2[j];
        const v2f bb = b1k2[j];
        const v2f w20 = w202[j], w21 = w212[j];
        const v2f g0  = wg02[j], g1  = wg12[j];
        v2f u[4], e[4], r[4], t[4];
        #pragma unroll
        for (int q = 0; q < 4; ++q)
            u[q] = vfma(xq[q], w1, bb);
        #pragma unroll
        for (int q = 0; q < 4; ++q) {
            e[q].x = __builtin_amdgcn_exp2f(u[q].x);
            e[q].y = __builtin_amdgcn_exp2f(u[q].y);
        }
        #pragma unroll
        for (int q = 0; q < 4; ++q) {
            const v2f dd = e[q] + one2;
            r[q].x = __builtin_amdgcn_rcpf(dd.x);
            r[q].y = __builtin_amdgcn_rcpf(dd.y);
        }
        #pragma unroll
        for (int q = 0; q < 4; ++q) {
            t[q] = vfma(m2, r[q], one2);             // tanh
            const v2f o = vfma(-t[q], t[q], one2);   // 1 - t^2
            const v2f g = t[q] * o;                  // t(1-t^2)
            P0[q] = vfma(w20, t[q], P0[q]);
            P1[q] = vfma(w21, t[q], P1[q]);
            A0[q] = vfma(g0,  g,    A0[q]);
            A1[q] = vfma(g1,  g,    A1[q]);
        }
    }

    const float b20 = b2[0], b21 = b2[1];
    float dens = 0.f, ndr = 0.f;
    float4 o01, o23, l4;
    float hp[8], nd4[4];
    #pragma unroll
    for (int q = 0; q < 4; ++q) {
        const float Vq   = (q == 0) ? Vv.x : (q == 1) ? Vv.y : (q == 2) ? Vv.z : Vv.w;
        const float psi0 = P0[q].x + P0[q].y + b20;
        const float psi1 = P1[q].x + P1[q].y + b21;
        const float ta0  = A0[q].x + A0[q].y;
        const float ta1  = A1[q].x + A1[q].y;
        const float hp0  = fmaf(Vq, psi0, ta0);      // h_psi = K*lap + V*psi
        const float hp1  = fmaf(Vq, psi1, ta1);
        hp[2*q]   = hp0;
        hp[2*q+1] = hp1;
        const float nd = fmaf(psi0, psi0, psi1 * psi1);
        nd4[q] = nd;
        dens += fmaf(psi0, hp0, psi1 * hp1);
        ndr  += nd;
    }
    o01.x = hp[0]; o01.y = hp[1]; o01.z = hp[2]; o01.w = hp[3];
    o23.x = hp[4]; o23.y = hp[5]; o23.z = hp[6]; o23.w = hp[7];
    reinterpret_cast<float4*>(out)[2*i]     = o01;
    reinterpret_cast<float4*>(out)[2*i + 1] = o23;
    l4.x = __builtin_amdgcn_logf(nd4[0]);            // log2(nd)
    l4.y = __builtin_amdgcn_logf(nd4[1]);
    l4.z = __builtin_amdgcn_logf(nd4[2]);
    l4.w = __builtin_amdgcn_logf(nd4[3]);
    reinterpret_cast<float4*>(lp2)[i] = l4;

    #pragma unroll
    for (int off = 32; off; off >>= 1) {
        dens += __shfl_down(dens, off);
        ndr  += __shfl_down(ndr, off);
    }
    __shared__ float sd[4], sn[4];
    const int lane = threadIdx.x & 63;
    const int wid  = threadIdx.x >> 6;
    if (lane == 0) { sd[wid] = dens; sn[wid] = ndr; }
    __syncthreads();
    if (threadIdx.x == 0) {
        pdens[blockIdx.x] = sd[0] + sd[1] + sd[2] + sd[3];
        pnd[blockIdx.x]   = sn[0] + sn[1] + sn[2] + sn[3];
    }
}

// ---------------------------------------------------------------------------
// Kernel 2, 2 blocks:
//   block0          : reduce 512 partials -> energy (~3 us, hidden)
//   block1 wave0.l0 : 100-step lookup walk on lp2 (2 adjacent loads + ~10
//                     VALU per step)
//   block1 waves1-3 : warm 1 MB of lp2 around init_idx into this XCD's L2,
//                     8 loads in flight per lane (~24 KB outstanding) so the
//                     warm finishes in ~9 us and is not the block's pole.
// ---------------------------------------------------------------------------
__global__ __launch_bounds__(256) void qpe_tail(
    const float* __restrict__ x,     const float* __restrict__ lp2,
    const float* __restrict__ pdens, const float* __restrict__ pnd,
    const float* __restrict__ noise, const int* __restrict__ init_idx,
    float* __restrict__ out,         float* __restrict__ dummy)
{
    const int tid = threadIdx.x;
    if (blockIdx.x == 0) {
        float d = pdens[tid] + pdens[tid + 256];
        float n = pnd[tid]   + pnd[tid + 256];
        #pragma unroll
        for (int off = 32; off; off >>= 1) {
            d += __shfl_down(d, off);
            n += __shfl_down(n, off);
        }
        __shared__ float sd[4], sn[4];
        const int lane = tid & 63;
        const int wid  = tid >> 6;
        if (lane == 0) { sd[wid] = d; sn[wid] = n; }
        __syncthreads();
        if (tid == 0) {
            const float Sd = sd[0] + sd[1] + sd[2] + sd[3];
            const float Sn = sn[0] + sn[1] + sn[2] + sn[3];
            out[2 * NPTS] = __fdiv_rn(Sd * DXF, fmaf(Sn, DXF, 1e-8f));
        }
        return;
    }

    if (tid == 0) {
        int c = init_idx[0];
        float zn = noise[0];
        for (int t = 0; t < STEPS; ++t) {
            const float zs = __fmul_rn(zn, SQRT2DT);
            const int tn = (t + 1 < STEPS) ? t + 1 : t;
            zn = noise[tn];                  // prefetch next step's noise
            float s = 0.0f;
            if (c > 0 && c < NPTS - 1) {
                const float l2m = lp2[c - 1];
                const float l2p = lp2[c + 1];
                s = __fmul_rn(__fsub_rn(l2p, l2m), LN2_O_2DX);
            }
            const float a = __fadd_rn(__fmul_rn(s, DTF), zs);
            const int shift = (int)__fdiv_rn(a, DXF);
            c += shift;
            c = c < 0 ? 0 : (c > NPTS - 1 ? NPTS - 1 : c);
        }
        out[2 * NPTS + 1] = x[c];
    } else if (tid >= 64) {
        // warm 1 MB (64K float4) of lp2 around init_idx, 8-deep pipeline
        int c0 = init_idx[0];
        int s4 = c0 / 4 - 32768;             // window start in float4 units
        if (s4 < 0) s4 = 0;
        if (s4 > NPTS / 4 - 65536) s4 = NPTS / 4 - 65536;
        const float4* __restrict__ src = (const float4*)lp2 + s4;
        const int l = tid - 64;              // 0..191
        float acc = 0.f;
        #pragma unroll 8
        for (int k = l; k < 65536; k += 192) {
            const float4 v = src[k];
            acc += v.x + v.y + v.z + v.w;
        }
        if (acc == 123456.789f) dummy[0] = acc;   // keep loads alive
    }
}

// ---------------------------------------------------------------------------
extern "C" void kernel_launch(void* const* d_in, const int* in_sizes, int n_in,
                              void* d_out, int out_size, void* d_ws, size_t ws_size,
                              hipStream_t stream) {
    const float* x        = (const float*)d_in[0];
    const float* V        = (const float*)d_in[1];
    const float* W1       = (const float*)d_in[2];
    const float* b1       = (const float*)d_in[3];
    const float* W2       = (const float*)d_in[4];
    const float* b2       = (const float*)d_in[5];
    const float* noise    = (const float*)d_in[6];
    const int*   init_idx = (const int*)d_in[7];

    float* out = (float*)d_out;
    float* ws  = (float*)d_ws;

    float* lp2   = ws;                    // N floats (2 MB)
    float* wk    = ws + NPTS;             // 1536
    float* pdens = ws + NPTS + 2048;      // 512
    float* pnd   = ws + NPTS + 3072;      // 512
    float* dummy = ws + NPTS + 4096;      // 1

    qpe_prep<<<1, 256, 0, stream>>>(W1, b1, W2, wk);
    qpe_main<<<NBLK4, 256, 0, stream>>>(x, V, wk, b2, out, lp2, pdens, pnd);
    qpe_tail<<<2, 256, 0, stream>>>(x, lp2, pdens, pnd, noise, init_idx,
                                    out, dummy);
}